// Round 16
// baseline (213.567 us; speedup 1.0000x reference)
//
#include <hip/hip_runtime.h>
#include <hip/hip_bf16.h>
#include <math.h>

#define B_   4
#define N_   6
#define CIN  512
#define CT   64
#define Dd   41
#define FH   16
#define FW   44
#define NPIX 704
#define NO   105
#define DSTR 48           // featD per-pixel stride
#define NXX  128
#define NYY  128
#define NZZ  1
#define TOT  (B_*NZZ*NYY*NXX)   // 65536
#define NPTS (B_*N_*Dd*NPIX)    // 692736
#define NCHUNK ((NPTS+63)/64)   // 10824

#define XSTRIDE 72   // bf16 elems per s_xT row
#define WSTRIDE 72   // bf16 elems per s_wd row

#define GEMM_BLOCKS 1056
#define GEOM_BLOCKS 4224

typedef __attribute__((ext_vector_type(8))) short short8;
typedef __attribute__((ext_vector_type(4))) float f32x4;

// ---------------- helpers ----------------

__device__ __forceinline__ unsigned short f2bf(float f) {   // RNE
    unsigned u = __float_as_uint(f);
    u += 0x7FFFu + ((u >> 16) & 1u);
    return (unsigned short)(u >> 16);
}

__device__ __forceinline__ unsigned pack_bf2(float a, float c) {
    return (unsigned)f2bf(a) | ((unsigned)f2bf(c) << 16);
}

__device__ __forceinline__ void inv3(const double* m, double* o) {
    double a=m[0],b=m[1],c=m[2],d=m[3],e=m[4],f=m[5],g=m[6],h=m[7],i=m[8];
    double A  =  (e*i - f*h);
    double Bc = -(d*i - f*g);
    double Cc =  (d*h - e*g);
    double det = a*A + b*Bc + c*Cc;
    double inv = 1.0/det;
    o[0]=A*inv;            o[1]=-(b*i - c*h)*inv;  o[2]= (b*f - c*e)*inv;
    o[3]=Bc*inv;           o[4]= (a*i - c*g)*inv;  o[5]=-(a*f - c*d)*inv;
    o[6]=Cc*inv;           o[7]=-(a*h - b*g)*inv;  o[8]= (a*e - b*d)*inv;
}

// geometry for lane l (= depth) of pixel pix, camera bn. returns kept/vox.
__device__ __forceinline__ void geom_lane(const double* s_tf, int b, int pix, int l,
                                          bool& kept, int& vox) {
    const int hh = pix / FW, ww = pix % FW;
    const double fx = (double)((float)(ww * (703.0/43.0)));
    const double fy = (double)((float)(hh * 17.0));
    const double px = fx - s_tf[21], py = fy - s_tf[22], mz = -s_tf[23];
    const double qx0 = s_tf[ 9]*px + s_tf[10]*py + s_tf[11]*mz, qx1 = s_tf[11];
    const double qy0 = s_tf[12]*px + s_tf[13]*py + s_tf[14]*mz, qy1 = s_tf[14];
    const double qz0 = s_tf[15]*px + s_tf[16]*py + s_tf[17]*mz, qz1 = s_tf[17];
    const double ux0 = s_tf[0]*qx0 + s_tf[1]*qy0 + s_tf[2], ux1 = s_tf[0]*qx1 + s_tf[1]*qy1;
    const double uy0 = s_tf[3]*qx0 + s_tf[4]*qy0 + s_tf[5], uy1 = s_tf[3]*qx1 + s_tf[4]*qy1;
    const double uz0 = s_tf[6]*qx0 + s_tf[7]*qy0 + s_tf[8], uz1 = s_tf[6]*qx1 + s_tf[7]*qy1;
    const double t0 = s_tf[18], t1 = s_tf[19], t2 = s_tf[20];

    const double DXD = (double)0.8f;
    const double LOX = (double)(-50.8f) - DXD*0.5;
    const double LOY = LOX;
    const double DZD = 20.0;
    const double LOZ = -10.0;

    kept = false; vox = 0;
    if (l < Dd) {
        double fz = 4.0 + (double)l;
        double qz = qz0 + qz1*fz;
        double sx = qz*(ux0 + ux1*fz) + t0;
        double sy = qz*(uy0 + uy1*fz) + t1;
        double sz = qz*(uz0 + uz1*fz) + t2;
        int gx = (int)((sx - LOX) / DXD);
        int gy = (int)((sy - LOY) / DXD);
        int gz = (int)((sz - LOZ) / DZD);
        kept = (gx>=0) & (gx<NXX) & (gy>=0) & (gy<NYY) & (gz>=0) & (gz<NZZ);
        vox  = (((b*NZZ + gz)*NYY + gy)*NXX + gx);
    }
}

// ---------------- kernel P: tiny prep = hist zero + tf + counter zero ----------------
__global__ __launch_bounds__(256) void prep_kernel(
    const float* __restrict__ rots, const float* __restrict__ trans,
    const float* __restrict__ intrins, const float* __restrict__ post_rots,
    const float* __restrict__ post_trans,
    double* __restrict__ tf, int* __restrict__ hist, int* __restrict__ counter)
{
    const int t = threadIdx.x;
    if (blockIdx.x < 256) {
        hist[blockIdx.x*256 + t] = 0;
    } else {
        if (t == 0) counter[0] = 0;
        if (t < B_*N_) {
            int bn = t;
            double k[9], pr[9], r[9], ik[9], ipr[9], c[9];
            for (int i=0;i<9;i++) { k[i]=intrins[bn*9+i]; pr[i]=post_rots[bn*9+i]; r[i]=rots[bn*9+i]; }
            inv3(k, ik);
            inv3(pr, ipr);
            for (int i=0;i<3;i++)
                for (int j=0;j<3;j++) {
                    double s = 0.0;
                    for (int kk=0;kk<3;kk++) s += r[i*3+kk]*ik[kk*3+j];
                    c[i*3+j] = s;
                }
            double* o = tf + bn*24;
            for (int i=0;i<9;i++) o[i]   = c[i];
            for (int i=0;i<9;i++) o[9+i] = ipr[i];
            for (int i=0;i<3;i++) o[18+i] = (double)trans[bn*3+i];
            for (int i=0;i<3;i++) o[21+i] = (double)post_trans[bn*3+i];
        }
    }
}

// ---------------- kernel GG: fused bf16 MFMA GEMM (inline convert) || geom+hist ----
// blocks 0..1055: gemm, per-k-tile staging of x (fp32->bf16) and Wd (fp32->bf16)
// into small LDS tiles (13.8 KB total). blocks 1056..5279: geometry + hist.
__global__ __launch_bounds__(256) void gemm_geom_kernel(
    const float* __restrict__ x, const float* __restrict__ Wd,
    const float* __restrict__ bd, const double* __restrict__ tf,
    float* __restrict__ featD, float* __restrict__ featB,
    int* __restrict__ hist, int* __restrict__ rank_arr)
{
    __shared__ unsigned short s_xT[64*XSTRIDE];   // 9.2 KB  [pix][k]
    __shared__ unsigned short s_wd[32*WSTRIDE];   // 4.6 KB  [o][k]
    __shared__ double s_tf[24];                   // geom path

    const int t    = threadIdx.x;
    const int l    = t & 63;
    const int wv   = t >> 6;

    if (blockIdx.x < GEMM_BLOCKS) {
        // ================= GEMM path =================
        const int col  = l & 15;
        const int quad = l >> 4;
        const int xcd = blockIdx.x & 7;
        const int q   = blockIdx.x >> 3;
        const int s   = q & 3;               // osplit
        const int pg  = q >> 2;
        const int p   = pg*8 + xcd;          // 0..263
        const int bn   = p / 11;
        const int tile = p % 11;
        const int pix0 = tile * 64;

        const int pix = pix0 + wv*16 + col;
        const float* xb = x + (size_t)bn * CIN * NPIX + pix0;

        // weight-staging thread mapping (fixed over k-loop)
        const int wo = t >> 3;               // 0..31 (o row within osplit)
        const int wc = t & 7;                // 8-float chunk
        const int og = s*32 + wo;            // global output row
        const float* wsrc = Wd + (size_t)og*CIN + wc*8;

        f32x4 acc[2];
        acc[0] = (f32x4){0.f,0.f,0.f,0.f};
        acc[1] = (f32x4){0.f,0.f,0.f,0.f};

        for (int k0 = 0; k0 < CIN; k0 += 64) {
            // ---- stage x tile: wave wv stages k rows [k0+wv*16, +16), lane = pix ----
            {
                unsigned pkx[8];
                #pragma unroll
                for (int j = 0; j < 8; j++) {
                    float a = xb[(size_t)(k0 + wv*16 + 2*j    )*NPIX + l];
                    float c = xb[(size_t)(k0 + wv*16 + 2*j + 1)*NPIX + l];
                    pkx[j] = pack_bf2(a, c);
                }
                unsigned* dst = (unsigned*)&s_xT[l*XSTRIDE + wv*16];
                *(uint4*)(dst + 0) = make_uint4(pkx[0],pkx[1],pkx[2],pkx[3]);
                *(uint4*)(dst + 4) = make_uint4(pkx[4],pkx[5],pkx[6],pkx[7]);
            }
            // ---- stage Wd tile: thread -> row wo, 8 k's at k0 + wc*8 ----
            {
                unsigned pkw[4];
                if (og < NO) {
                    const float* wp = wsrc + k0;
                    #pragma unroll
                    for (int i = 0; i < 4; i++)
                        pkw[i] = pack_bf2(wp[2*i], wp[2*i+1]);
                } else {
                    pkw[0] = pkw[1] = pkw[2] = pkw[3] = 0u;
                }
                *(uint4*)&s_wd[wo*WSTRIDE + wc*8] = make_uint4(pkw[0],pkw[1],pkw[2],pkw[3]);
            }
            __syncthreads();

            #pragma unroll
            for (int ks = 0; ks < 2; ks++) {
                short8 bfr = *(const short8*)&s_xT[(wv*16 + col)*XSTRIDE + ks*32 + quad*8];
                #pragma unroll
                for (int j = 0; j < 2; j++) {
                    short8 afr = *(const short8*)&s_wd[(j*16 + col)*WSTRIDE + ks*32 + quad*8];
                    acc[j] = __builtin_amdgcn_mfma_f32_16x16x32_bf16(afr, bfr, acc[j], 0, 0, 0);
                }
            }
            __syncthreads();
        }

        const size_t prow = (size_t)(bn*NPIX + pix);
        #pragma unroll
        for (int j = 0; j < 2; j++) {
            #pragma unroll
            for (int rr = 0; rr < 4; rr++) {
                int o = (2*s + j)*16 + quad*4 + rr;
                if (o < Dd) {
                    featD[prow*DSTR + o] = acc[j][rr] + bd[o];
                } else if (o < NO) {
                    featB[prow*CT + (o - Dd)] = acc[j][rr] + bd[o];
                }
            }
        }
    } else {
        // ================= geometry + hist path =================
        const int bid2 = blockIdx.x - GEMM_BLOCKS;                 // 0..4223
        const int bid  = (bid2 & 7) * 528 + (bid2 >> 3);           // XCD locality
        const int bn  = bid / 176;
        const int pix = (bid % 176)*4 + wv;
        const int b   = bn / N_;

        if (t < 24) s_tf[t] = tf[bn*24 + t];
        __syncthreads();

        bool kept; int vox;
        geom_lane(s_tf, b, pix, l, kept, vox);
        if (kept) {
            int rank = atomicAdd(&hist[vox], 1);
            rank_arr[(size_t)(bn*NPIX + pix)*Dd + l] = rank;
        }
    }
}

// ---------------- scan: local scan + last-block folds the bsum scan ----------------
__global__ __launch_bounds__(256) void scan_kernel(const int* __restrict__ hist,
                                                   int* __restrict__ offs,
                                                   int* __restrict__ bsum,
                                                   int* __restrict__ np,
                                                   int* __restrict__ counter,
                                                   float4* __restrict__ scat4) {
    __shared__ int s[256];
    __shared__ int lastdone;
    const int t = threadIdx.x;
    const int i = blockIdx.x*256 + t;
    int val = hist[i];
    s[t] = val;
    __syncthreads();

    // zero 64KB of scat while the scan barriers churn (16 float4 per thread)
    {
        float4 z = make_float4(0.f, 0.f, 0.f, 0.f);
        float4* dst = scat4 + (size_t)blockIdx.x*4096 + t;
        #pragma unroll
        for (int j = 0; j < 16; j++) dst[j*256] = z;
    }

    #pragma unroll
    for (int off = 1; off < 256; off <<= 1) {
        __syncthreads();
        int u = (t >= off) ? s[t-off] : 0;
        __syncthreads();
        s[t] += u;
    }
    __syncthreads();
    offs[i] = s[t] - val;                  // block-local exclusive
    if (t == 255) bsum[blockIdx.x] = s[255];

    // last block to finish scans the 256 block sums
    __threadfence();
    if (t == 0) lastdone = (atomicAdd(counter, 1) == 255) ? 1 : 0;
    __syncthreads();
    if (lastdone) {
        __threadfence();
        int v = bsum[t];
        s[t] = v;
        __syncthreads();
        #pragma unroll
        for (int off = 1; off < 256; off <<= 1) {
            int u = (t >= off) ? s[t-off] : 0;
            __syncthreads();
            s[t] += u;
            __syncthreads();
        }
        bsum[t] = s[t] - v;
        if (t == 255) np[0] = s[255];
    }
}

// ---------------- kernel S2: softmax + geometry + atomic-free record scatter --------
__global__ __launch_bounds__(256) void sm_scatter_kernel(
    const float* __restrict__ featD, const double* __restrict__ tf,
    const int* __restrict__ offs, const int* __restrict__ bsum,
    const int* __restrict__ rank_arr, uint2* __restrict__ rec)
{
    __shared__ double s_tf[24];
    const int bid = (blockIdx.x & 7) * 528 + (blockIdx.x >> 3);   // XCD locality
    const int t   = threadIdx.x;
    const int l   = t & 63;
    const int wv  = t >> 6;
    const int bn  = bid / 176;
    const int pix = (bid % 176)*4 + wv;
    const int b   = bn / N_;

    if (t < 24) s_tf[t] = tf[bn*24 + t];
    __syncthreads();

    const size_t prow = (size_t)(bn*NPIX + pix);

    // ---- softmax across lanes (d = lane, 41 active) ----
    float logit = (l < Dd) ? featD[prow*DSTR + l] : -3.0e38f;
    float mm = logit;
    #pragma unroll
    for (int off = 32; off > 0; off >>= 1) mm = fmaxf(mm, __shfl_xor(mm, off));
    float e = (l < Dd) ? expf(logit - mm) : 0.0f;
    float ssum = e;
    #pragma unroll
    for (int off = 32; off > 0; off >>= 1) ssum += __shfl_xor(ssum, off);
    const float wgt = e / ssum;

    // ---- geometry + position from offs + bsum + rank (no atomics) ----
    bool kept; int vox;
    geom_lane(s_tf, b, pix, l, kept, vox);
    if (kept) {
        int pos = offs[vox] + bsum[vox >> 8] + rank_arr[prow*Dd + l];
        unsigned pk = ((unsigned)vox << 15) | (unsigned)prow;
        rec[pos] = make_uint2(pk, __float_as_uint(wgt));
    }
}

// ---------------- kernel E: balanced segmented gather -> scat[vox][ct] ----------------
__global__ __launch_bounds__(256) void gather_kernel(
    const uint2* __restrict__ rec, const int* __restrict__ np,
    const float* __restrict__ featB, float* __restrict__ scat)
{
    const int bid = (blockIdx.x & 7) * 339 + (blockIdx.x >> 3);   // XCD locality
    const int t  = threadIdx.x;
    const int wv = t >> 6;
    const int l  = t & 63;
    const int chunk = bid * 4 + wv;
    const int base  = chunk * 64;
    const int Np = np[0];                  // total valid points
    if (base >= Np) return;
    int cnt = Np - base; if (cnt > 64) cnt = 64;

    unsigned pk = 0; float w = 0.0f;
    if (l < cnt) { uint2 r = rec[base + l]; pk = r.x; w = __uint_as_float(r.y); }
    unsigned pkm = __shfl(pk, (l == 0) ? 0 : (l - 1));
    unsigned long long starts =
        __ballot((l > 0) && (l < cnt) && ((pk >> 15) != (pkm >> 15)));

    unsigned long long m = starts;
    int rs = 0;
    while (rs < cnt) {
        int re = m ? (__ffsll((unsigned long long)m) - 1) : cnt;
        if (m) m &= m - 1;
        float acc = 0.0f;
        for (int j = rs; j < re; j++) {
            unsigned pkj = __shfl(pk, j);
            float    wj  = __shfl(w, j);
            unsigned id  = pkj & 0x7FFFu;
            acc += wj * featB[(size_t)id * CT + l];
        }
        unsigned vrun = __shfl(pk, rs) >> 15;
        float* dst = scat + (size_t)vrun * CT + l;
        if (rs == 0 || re == cnt) {
            unsafeAtomicAdd(dst, acc);      // run may continue in adjacent chunk
        } else {
            *dst = acc;                     // voxel wholly owned by this chunk
        }
        rs = re;
    }
}

// ---------------- kernel F: transpose (b,pix,ct) -> (b,ct,pix) ----------------
__global__ __launch_bounds__(256) void transpose_k(const float* __restrict__ scat,
                                                   float* __restrict__ out) {
    __shared__ float tile[64][65];
    int b  = blockIdx.x >> 8;
    int t0 = (blockIdx.x & 255) * 64;
    const float* src = scat + (size_t)b * (NYY*NXX) * CT;
    #pragma unroll
    for (int i=0;i<16;i++) {
        int idx = threadIdx.x + i*256;
        int p = idx >> 6, c = idx & 63;
        tile[p][c] = src[(size_t)(t0+p)*CT + c];
    }
    __syncthreads();
    float* dst = out + (size_t)b * CT * (NYY*NXX);
    #pragma unroll
    for (int i=0;i<16;i++) {
        int idx = threadIdx.x + i*256;
        int c = idx >> 6, p = idx & 63;
        dst[(size_t)c*(NYY*NXX) + t0 + p] = tile[p][c];
    }
}

// ---------------- launcher ----------------
extern "C" void kernel_launch(void* const* d_in, const int* in_sizes, int n_in,
                              void* d_out, int out_size, void* d_ws, size_t ws_size,
                              hipStream_t stream) {
    const float* x          = (const float*)d_in[0];
    const float* rots       = (const float*)d_in[1];
    const float* trans      = (const float*)d_in[2];
    const float* intrins    = (const float*)d_in[3];
    const float* post_rots  = (const float*)d_in[4];
    const float* post_trans = (const float*)d_in[5];
    const float* Wd         = (const float*)d_in[6];
    const float* bd         = (const float*)d_in[7];
    float* out = (float*)d_out;

    char* ws = (char*)d_ws;
    float*          featB  = (float*)ws;          ws += (size_t)B_*N_*NPIX*CT*4;    // 4.33 MB
    float*          featD  = (float*)ws;          ws += (size_t)B_*N_*NPIX*DSTR*4;  // 3.25 MB
    float*          scat   = (float*)ws;          ws += (size_t)TOT*CT*4;           // 16.78 MB
    int*            rank_a = (int*)ws;            ws += (size_t)NPTS*4;             // 2.77 MB
    uint2*          rec    = (uint2*)ws;          ws += (size_t)NPTS*8;             // 5.54 MB
    int*            hist   = (int*)ws;            ws += (size_t)TOT*4;              // 0.26 MB
    int*            offs   = (int*)ws;            ws += (size_t)TOT*4;              // 0.26 MB
    int*            bsum   = (int*)ws;            ws += 256*4;
    int*            np     = (int*)ws;            ws += 256;
    int*            counter= (int*)ws;            ws += 256;
    double*         tf     = (double*)ws;         ws += (size_t)B_*N_*24*8;         // 4.6 KB

    prep_kernel<<<257, 256, 0, stream>>>(rots, trans, intrins, post_rots, post_trans,
                                         tf, hist, counter);
    gemm_geom_kernel<<<GEMM_BLOCKS + GEOM_BLOCKS, 256, 0, stream>>>(
        x, Wd, bd, tf, featD, featB, hist, rank_a);
    scan_kernel<<<TOT/256, 256, 0, stream>>>(hist, offs, bsum, np, counter, (float4*)scat);
    sm_scatter_kernel<<<B_*N_*176, 256, 0, stream>>>(featD, tf, offs, bsum, rank_a, rec);
    gather_kernel<<<2712, 256, 0, stream>>>(rec, np, featB, scat);
    transpose_k<<<B_*(NYY*NXX/64), 256, 0, stream>>>(scat, out);
}